// Round 9
// baseline (532.208 us; speedup 1.0000x reference)
//
#include <hip/hip_runtime.h>
#include <hip/hip_bf16.h>
#include <float.h>

#define N_E   1024
#define CD    128
#define DELTA 0.45f

typedef __attribute__((ext_vector_type(4))) float f32x4;
typedef __attribute__((ext_vector_type(8))) short bf16x8;

static __device__ inline unsigned short f2bf(float f) {
    unsigned u = __float_as_uint(f);
    unsigned r = (u + 0x7fffu + ((u >> 16) & 1u)) >> 16;
    return (unsigned short)r;
}

// ---------------- Kernel 1: embed = emb @ proj_w^T + b ; ee ; ehi bf16
__global__ __launch_bounds__(128) void k_embed(const float* __restrict__ emb,
                                               const float* __restrict__ pw,
                                               const float* __restrict__ pb,
                                               float* __restrict__ embed,
                                               float* __restrict__ ee,
                                               unsigned short* __restrict__ ehi) {
    int j = blockIdx.x;
    int c = threadIdx.x;
    __shared__ float er[CD];
    __shared__ float red[CD];
    er[c] = emb[(size_t)j * CD + c];
    __syncthreads();
    float acc = pb[c];
    const float* pwr = pw + (size_t)c * CD;
    #pragma unroll 8
    for (int k = 0; k < CD; ++k) acc += er[k] * pwr[k];
    embed[(size_t)j * CD + c] = acc;
    ehi[(size_t)j * CD + c] = f2bf(acc);
    red[c] = acc * acc;
    __syncthreads();
    for (int off = 64; off > 0; off >>= 1) {
        if (c < off) red[c] += red[c + off];
        __syncthreads();
    }
    if (c == 0) ee[j] = red[0];
}

// ---------------- Kernel 2: 8 waves, codebook-in-registers (N-split), no hot-loop sync
__global__ __launch_bounds__(512, 2) void k_vq(const float* __restrict__ x,
                                               const float* __restrict__ ee,
                                               const unsigned short* __restrict__ ehi,
                                               const float* __restrict__ embed,
                                               float* __restrict__ out_xq,
                                               float* __restrict__ out_idx,
                                               float* __restrict__ partials) {
    // region: x-tile [64 q][128 c] bf16-hi, chunk cc of row m at cc^SW(m), SW(m)=(m&15)^(m>>4).
    // Later aliased as fp32 recheck scratch.
    __shared__ alignas(64) unsigned short region[64 * 128];
    __shared__ float ee_s[N_E];                 // phase A alias: qqpart[16][64]
    __shared__ float qq[64];
    __shared__ alignas(16) float wstate[8 * 64 * 4];   // per (wave,q): b1, j1bits, b2, S
    __shared__ int   bestjs[64];
    __shared__ unsigned long long flagmask_s;

    const int t    = threadIdx.x;
    const int w    = t >> 6;                    // 8 waves; wave owns codes [w*128, w*128+128)
    const int lane = t & 63;
    const int lo4  = lane & 15;
    const int hi2  = lane >> 4;
    const int blk  = blockIdx.x;
    const int qbase = blk * 64;
    const int b    = blk >> 4;
    const int hw0  = (blk & 15) * 64;
    const float* xb = x + (size_t)b * 131072;
    const int wc0  = w * 128;

    // ---- phase A (waves 0-3): stage x-tile as bf16-hi (swizzled) + qq partials
    if (t < 256) {
        const int f4 = t & 15;      // queries 4*f4 .. 4*f4+3
        const int cg = t >> 4;      // channels cg*8 .. cg*8+7
        float4 v[8];
        #pragma unroll
        for (int r = 0; r < 8; ++r)
            v[r] = *reinterpret_cast<const float4*>(
                xb + (size_t)(cg * 8 + r) * 1024 + hw0 + 4 * f4);
        #pragma unroll
        for (int i = 0; i < 4; ++i) {
            const int m = 4 * f4 + i;
            const int sw = (m & 15) ^ (m >> 4);
            short hh[8];
            float q2 = 0.f;
            #pragma unroll
            for (int r = 0; r < 8; ++r) {
                const float f = (&v[r].x)[i];
                q2 = fmaf(f, f, q2);
                hh[r] = (short)f2bf(f);
            }
            *reinterpret_cast<bf16x8*>(&region[m * 128 + ((cg ^ sw) << 3)]) =
                bf16x8{hh[0], hh[1], hh[2], hh[3], hh[4], hh[5], hh[6], hh[7]};
            ee_s[cg * 64 + m] = q2;   // qqpart alias
        }
    }

    // ---- B: wave's 128 codes into registers (8 n-tiles x 4 k-chunks), from L2
    bf16x8 breg[8][4];
    #pragma unroll
    for (int nt = 0; nt < 8; ++nt)
        #pragma unroll
        for (int kc = 0; kc < 4; ++kc)
            breg[nt][kc] = *reinterpret_cast<const bf16x8*>(
                &ehi[(size_t)(wc0 + nt * 16 + lo4) * CD + kc * 32 + hi2 * 8]);

    __syncthreads();
    if (t < 64) {
        float s = 0.f;
        #pragma unroll
        for (int c2 = 0; c2 < 16; ++c2) s += ee_s[c2 * 64 + t];
        qq[t] = s;
    }
    __syncthreads();
    for (int i = t; i < N_E; i += 512) ee_s[i] = ee[i];
    __syncthreads();   // ee_s + qq + region all ready

    // ---- hot loop: 2 passes x 32 queries; zero syncs, zero global traffic
    #pragma unroll 1
    for (int p = 0; p < 2; ++p) {
        // A-fragments for rows p*32 .. p*32+31
        bf16x8 a[2][4];
        float qq_s[8];
        #pragma unroll
        for (int mti = 0; mti < 2; ++mti) {
            const int mt = p * 2 + mti;
            const int row = mt * 16 + lo4;
            const int sw = lo4 ^ mt;
            #pragma unroll
            for (int ks = 0; ks < 4; ++ks) {
                const int kcq = ks * 4 + hi2;
                a[mti][ks] = *reinterpret_cast<const bf16x8*>(
                    &region[row * 128 + ((kcq ^ sw) << 3)]);
            }
            #pragma unroll
            for (int r = 0; r < 4; ++r) qq_s[mti * 4 + r] = qq[mt * 16 + hi2 * 4 + r];
        }

        float b1[8], b2[8], sacc[8];
        int   j1[8];
        #pragma unroll
        for (int s = 0; s < 8; ++s) { b1[s] = FLT_MAX; b2[s] = FLT_MAX; sacc[s] = 0.f; j1[s] = 0; }

        #pragma unroll
        for (int nt = 0; nt < 8; ++nt) {
            const int n = wc0 + nt * 16 + lo4;
            const float ee_r = ee_s[n];
            #pragma unroll
            for (int mti = 0; mti < 2; ++mti) {
                f32x4 acc = {0.f, 0.f, 0.f, 0.f};
                #pragma unroll
                for (int ks = 0; ks < 4; ++ks)
                    acc = __builtin_amdgcn_mfma_f32_16x16x32_bf16(a[mti][ks], breg[nt][ks], acc, 0, 0, 0);
                #pragma unroll
                for (int r = 0; r < 4; ++r) {
                    const int slot = mti * 4 + r;
                    float d2 = fmaf(-2.f, acc[r], qq_s[slot] + ee_r);
                    d2 = fmaxf(d2, 0.f);
                    b2[slot] = fminf(b2[slot], fmaxf(b1[slot], d2));
                    const bool lt = d2 < b1[slot];
                    j1[slot] = lt ? n : j1[slot];
                    b1[slot] = lt ? d2 : b1[slot];
                    sacc[slot] += __expf(16.f - sqrtf(d2));
                }
            }
        }

        // ---- 16-lane merge per slot; write per-wave state
        #pragma unroll
        for (int slot = 0; slot < 8; ++slot) {
            float B1 = b1[slot]; int J1 = j1[slot]; float B2 = b2[slot]; float S = sacc[slot];
            #pragma unroll
            for (int d = 1; d <= 8; d <<= 1) {
                const float o1 = __shfl_xor(B1, d);
                const int   oj = __shfl_xor(J1, d);
                const float o2 = __shfl_xor(B2, d);
                const float os = __shfl_xor(S, d);
                const float mx = fmaxf(B1, o1);
                B2 = fminf(fminf(B2, o2), mx);
                const bool take = (o1 < B1) || (o1 == B1 && oj < J1);
                B1 = take ? o1 : B1;
                J1 = take ? oj : J1;
                S += os;
            }
            if (lo4 == 0) {
                const int q = (p * 2 + (slot >> 2)) * 16 + hi2 * 4 + (slot & 3);
                f32x4 st = {B1, __int_as_float(J1), B2, S};
                *reinterpret_cast<f32x4*>(&wstate[(w * 64 + q) * 4]) = st;
            }
        }
    }
    __syncthreads();

    // ---- cross-wave merge (codes split across waves), flags, loss partial
    if (t < 64) {
        float B1 = FLT_MAX; int J1 = 0; float B2 = FLT_MAX; float S = 0.f;
        #pragma unroll
        for (int ww = 0; ww < 8; ++ww) {
            const f32x4 st = *reinterpret_cast<const f32x4*>(&wstate[(ww * 64 + t) * 4]);
            const float c1 = st[0]; const int i1 = __float_as_int(st[1]);
            const float c2 = st[2]; const float cs = st[3];
            const float mx = fmaxf(B1, c1);
            B2 = fminf(fminf(B2, c2), mx);
            const bool take = (c1 < B1) || (c1 == B1 && i1 < J1);
            B1 = take ? c1 : B1;
            J1 = take ? i1 : J1;
            S += cs;
        }
        bestjs[t] = J1;
        out_idx[qbase + t] = (float)J1;
        const bool fl = (B2 - B1) < DELTA;
        const unsigned long long bal = __ballot(fl);
        if (t == 0) flagmask_s = bal;
        float lossi = sqrtf(fmaxf(B1, 0.f)) - 16.f + __logf(S);
        #pragma unroll
        for (int d = 32; d; d >>= 1) lossi += __shfl_down(lossi, d);
        if (t == 0) partials[blk] = lossi;
    }
    __syncthreads();

    // ---- exact fp32 recheck for near-tie queries (distributed over 8 waves)
    float* qbufw = reinterpret_cast<float*>(region) + w * 128;
    unsigned long long fm = flagmask_s;
    int kq = 0;
    while (fm) {
        const int m = __builtin_ctzll(fm);
        fm &= fm - 1;
        if ((kq & 7) == w) {
            const int hw = hw0 + m;
            qbufw[lane]      = xb[(size_t)lane * 1024 + hw];
            qbufw[64 + lane] = xb[(size_t)(lane + 64) * 1024 + hw];
            __threadfence_block();
            const float qqm = qq[m];
            float dbest = FLT_MAX; int jbest = 0;
            for (int tt = 0; tt < 16; ++tt) {
                const int j = tt * 64 + lane;
                float dot = 0.f;
                #pragma unroll 8
                for (int c4 = 0; c4 < 32; ++c4) {
                    const f32x4 evv = *reinterpret_cast<const f32x4*>(&embed[j * CD + 4 * c4]);
                    const f32x4 qv  = *reinterpret_cast<const f32x4*>(&qbufw[4 * c4]);
                    dot = fmaf(evv[0], qv[0], dot);
                    dot = fmaf(evv[1], qv[1], dot);
                    dot = fmaf(evv[2], qv[2], dot);
                    dot = fmaf(evv[3], qv[3], dot);
                }
                float d2 = fmaf(-2.f, dot, qqm + ee_s[j]);
                d2 = fmaxf(d2, 0.f);
                if (d2 < dbest || (d2 == dbest && j < jbest)) { dbest = d2; jbest = j; }
            }
            #pragma unroll
            for (int d = 1; d <= 32; d <<= 1) {
                const float od = __shfl_xor(dbest, d);
                const int   oj = __shfl_xor(jbest, d);
                if (od < dbest || (od == dbest && oj < jbest)) { dbest = od; jbest = oj; }
            }
            if (lane == 0) {
                bestjs[m] = jbest;
                out_idx[qbase + m] = (float)jbest;
            }
        }
        ++kq;
    }
    __syncthreads();

    // ---- gather x_q (512 threads: 16 query-groups x 32 channel-groups)
    const int f4g = t & 15;
    const int cgg = t >> 4;          // 0..31, 4 channels each
    const int jq0 = bestjs[4 * f4g + 0];
    const int jq1 = bestjs[4 * f4g + 1];
    const int jq2 = bestjs[4 * f4g + 2];
    const int jq3 = bestjs[4 * f4g + 3];
    float* ob = out_xq + (size_t)b * 131072 + hw0 + 4 * f4g;
    #pragma unroll
    for (int r = 0; r < 4; ++r) {
        const int c = cgg * 4 + r;
        float4 v;
        v.x = embed[jq0 * CD + c];
        v.y = embed[jq1 * CD + c];
        v.z = embed[jq2 * CD + c];
        v.w = embed[jq3 * CD + c];
        *reinterpret_cast<float4*>(ob + (size_t)c * 1024) = v;
    }
}

// ---------------- Kernel 3: deterministic loss reduction
__global__ __launch_bounds__(256) void k_loss(const float* __restrict__ partials,
                                              float* __restrict__ out_loss) {
    __shared__ float red[256];
    const int t = threadIdx.x;
    float v = 0.f;
    for (int i = t; i < 1024; i += 256) v += partials[i];
    red[t] = v;
    __syncthreads();
    for (int off = 128; off; off >>= 1) {
        if (t < off) red[t] += red[t + off];
        __syncthreads();
    }
    if (t == 0) out_loss[0] = red[0] * (1.0f / 65536.0f);
}

extern "C" void kernel_launch(void* const* d_in, const int* in_sizes, int n_in,
                              void* d_out, int out_size, void* d_ws, size_t ws_size,
                              hipStream_t stream) {
    const float* x   = (const float*)d_in[0];   // (64,128,32,32)
    const float* emb = (const float*)d_in[1];   // (1024,128)
    const float* pw  = (const float*)d_in[2];   // (128,128)
    const float* pb  = (const float*)d_in[3];   // (128,)

    float* out = (float*)d_out;
    float* out_xq   = out;                 // 8388608 floats
    float* out_loss = out + 8388608;       // 1 float
    float* out_idx  = out + 8388609;       // 65536 floats

    float* embed    = (float*)d_ws;                       // 1024*128 fp32
    float* ee       = embed + N_E * CD;                   // 1024
    float* partials = ee + N_E;                           // 1024
    unsigned short* ehi = (unsigned short*)(partials + 1024);   // 1024*128 bf16

    k_embed<<<N_E, 128, 0, stream>>>(emb, pw, pb, embed, ee, ehi);
    k_vq<<<1024, 512, 0, stream>>>(x, ee, ehi, embed, out_xq, out_idx, partials);
    k_loss<<<1, 256, 0, stream>>>(partials, out_loss);
}